// Round 7
// baseline (475.360 us; speedup 1.0000x reference)
//
#include <hip/hip_runtime.h>

#define NN 100000
#define NE 1600000
#define NG 512
#define NC 16
#define HC 8  // histogram copies

static inline int cdiv(long long a, int b) { return (int)((a + b - 1) / b); }

__global__ void k_zero_i(int* p, int n) {
  int i = blockIdx.x * blockDim.x + threadIdx.x;
  if (i < n) p[i] = 0;
}

// 8-way replicated in-degree histogram: cnt[d*HC + (e&7)]
__global__ void k_hist8(const int* __restrict__ dst, int* __restrict__ cnt) {
  int e = blockIdx.x * blockDim.x + threadIdx.x;
  if (e < NE) atomicAdd(&cnt[dst[e] * HC + (e & (HC - 1))], 1);
}

// sum copies -> count, dinv
__global__ void k_reduce(const int* __restrict__ cnt, int* __restrict__ count,
                         float* __restrict__ dinv) {
  int i = blockIdx.x * blockDim.x + threadIdx.x;
  if (i >= NN) return;
  int s = 0;
#pragma unroll
  for (int c = 0; c < HC; ++c) s += cnt[i * HC + c];
  count[i] = s;
  dinv[i] = rsqrtf((float)(s + 1));  // +1 self loop
}

// graph boundaries from sorted batch: gstart[g] = first node index with batch >= g
__global__ void k_bounds(const int* __restrict__ batch, int* __restrict__ gstart) {
  int i = blockIdx.x * blockDim.x + threadIdx.x;
  if (i > NN) return;
  int b = (i < NN) ? batch[i] : NG;
  int bp = (i > 0) ? batch[i - 1] : -1;
  for (int g = bp + 1; g <= b; ++g) gstart[g] = i;
}

// exclusive scan, 256/block; bsum gets block totals
__global__ void k_scan1(const int* __restrict__ in, int* __restrict__ out,
                        int* __restrict__ bsum, int n) {
  __shared__ int s[256];
  int t = threadIdx.x, i = blockIdx.x * 256 + t;
  int v = (i < n) ? in[i] : 0;
  s[t] = v;
  __syncthreads();
  for (int d = 1; d < 256; d <<= 1) {
    int a = (t >= d) ? s[t - d] : 0;
    __syncthreads();
    s[t] += a;
    __syncthreads();
  }
  if (i < n) out[i] = s[t] - v;  // exclusive
  if (t == 255) bsum[blockIdx.x] = s[255];
}

// single-block exclusive scan over <=512 values
__global__ void k_scan2(const int* __restrict__ in, int* __restrict__ out, int nb) {
  __shared__ int s[512];
  int t = threadIdx.x;
  int v = (t < nb) ? in[t] : 0;
  s[t] = v;
  __syncthreads();
  for (int d = 1; d < 512; d <<= 1) {
    int a = (t >= d) ? s[t - d] : 0;
    __syncthreads();
    s[t] += a;
    __syncthreads();
  }
  if (t < nb) out[t] = s[t] - v;
}

// finalize offs and init fillc[i*HC+c] with ABSOLUTE start position of bucket (i,c)
__global__ void k_scan3(int* __restrict__ offs, const int* __restrict__ bpref,
                        const int* __restrict__ cnt, int* __restrict__ fillc) {
  int i = blockIdx.x * blockDim.x + threadIdx.x;
  if (i >= NN) return;
  int run = offs[i] + bpref[i >> 8];
  offs[i] = run;
#pragma unroll
  for (int c = 0; c < HC; ++c) {
    fillc[i * HC + c] = run;
    run += cnt[i * HC + c];
  }
}

// scatter edges into CSR slots: single atomic returns absolute position
__global__ void k_fill(const int* __restrict__ src, const int* __restrict__ dst,
                       int* __restrict__ fillc, int* __restrict__ csr) {
  int e = blockIdx.x * blockDim.x + threadIdx.x;
  if (e >= NE) return;
  int pos = atomicAdd(&fillc[dst[e] * HC + (e & (HC - 1))], 1);
  csr[pos] = src[e];
}

// gather-reduce aggregation; weight dinv[s]*dinv[i] computed on the fly.
// BR: fused bias+relu epilogue.
template <int F, int LPN, bool BR>
__global__ void k_agg(const float* __restrict__ h, const int* __restrict__ csr,
                      const int* __restrict__ offs, const int* __restrict__ count,
                      const float* __restrict__ dinv, const float* __restrict__ bias,
                      float* __restrict__ out) {
  int wave = threadIdx.x >> 6, lane = threadIdx.x & 63;
  const int NPW = 64 / LPN;  // nodes per wave
  int i = (blockIdx.x * 4 + wave) * NPW + ((LPN == 64) ? 0 : (lane >> 4));
  int f = lane & (LPN - 1);
  if (i >= NN) return;
  int off = offs[i], cnt = count[i];
  float di = dinv[i];
  float acc0 = 0.f, acc1 = 0.f, acc2 = 0.f, acc3 = 0.f;
  int j = 0;
  for (; j + 3 < cnt; j += 4) {
    int s0 = csr[off + j], s1 = csr[off + j + 1];
    int s2 = csr[off + j + 2], s3 = csr[off + j + 3];
    float w0 = dinv[s0] * di, w1 = dinv[s1] * di;
    float w2 = dinv[s2] * di, w3 = dinv[s3] * di;
    acc0 += h[(size_t)s0 * F + f] * w0;
    acc1 += h[(size_t)s1 * F + f] * w1;
    acc2 += h[(size_t)s2 * F + f] * w2;
    acc3 += h[(size_t)s3 * F + f] * w3;
  }
  for (; j < cnt; ++j) {
    int s0 = csr[off + j];
    acc0 += h[(size_t)s0 * F + f] * (dinv[s0] * di);
  }
  acc0 += h[(size_t)i * F + f] * di * di;  // self loop
  float v = (acc0 + acc1) + (acc2 + acc3);
  if (BR) v = fmaxf(v + bias[f], 0.f);
  out[(size_t)i * F + f] = v;
}

// out[i,o] = a[i,:]@W[:,o] (+bias, relu if BR)
template <int FIN, int FOUT, bool BR>
__global__ void k_dense(const float* __restrict__ a, const float* __restrict__ W,
                        const float* __restrict__ b, float* __restrict__ out, int n) {
  __shared__ float sW[FIN * FOUT];
  __shared__ float sb[FOUT];
  for (int t = threadIdx.x; t < FIN * FOUT; t += blockDim.x) sW[t] = W[t];
  if (BR)
    for (int t = threadIdx.x; t < FOUT; t += blockDim.x) sb[t] = b[t];
  __syncthreads();
  int idx = blockIdx.x * blockDim.x + threadIdx.x;
  int i = idx / FOUT, o = idx % FOUT;
  if (i >= n) return;
  float acc = BR ? sb[o] : 0.f;
#pragma unroll
  for (int k = 0; k < FIN; ++k) acc += a[(size_t)i * FIN + k] * sW[k * FOUT + o];
  out[idx] = BR ? fmaxf(acc, 0.0f) : acc;
}

// fused dense3(64->128)+relu+segmented mean-pool over sorted batch.
#define D3_NPB 128  // nodes per block
#define D3_CH 32    // nodes per staged chunk
__global__ void k_dense3_pool3(const float* __restrict__ a, const float* __restrict__ W3,
                               const float* __restrict__ b3, const int* __restrict__ batch,
                               float* __restrict__ gsum) {
  __shared__ float sa[D3_CH * 64];
  int t = threadIdx.x;
  int half = t >> 7, o = t & 127;
  float wcol[64];
#pragma unroll
  for (int k = 0; k < 64; ++k) wcol[k] = W3[k * 128 + o];
  float bias = b3[o];
  int base = blockIdx.x * D3_NPB;
  float acc = 0.f;
  int curg = -1;
#pragma unroll 1
  for (int c0 = 0; c0 < D3_NPB; c0 += D3_CH) {
    __syncthreads();
#pragma unroll
    for (int r = 0; r < (D3_CH * 16) / 256; ++r) {
      int idx = r * 256 + t;  // float4 index within chunk
      int node = base + c0 + (idx >> 4);
      float4 v = make_float4(0.f, 0.f, 0.f, 0.f);
      if (node < NN) v = ((const float4*)(a + (size_t)node * 64))[idx & 15];
      ((float4*)sa)[idx] = v;
    }
    __syncthreads();
#pragma unroll 1
    for (int j = 0; j < D3_CH / 2; ++j) {
      int local = half * (D3_CH / 2) + j;
      int n = base + c0 + local;
      if (n >= NN) break;
      const float* row = sa + local * 64;
      float v = bias;
#pragma unroll
      for (int q = 0; q < 16; ++q) {
        float4 av = ((const float4*)row)[q];
        v += av.x * wcol[4 * q] + av.y * wcol[4 * q + 1] + av.z * wcol[4 * q + 2] +
             av.w * wcol[4 * q + 3];
      }
      int g = batch[n];
      if (g != curg) {
        if (curg >= 0) atomicAdd(&gsum[curg * 128 + o], acc);
        curg = g;
        acc = 0.f;
      }
      acc += fmaxf(v, 0.f);
    }
  }
  if (curg >= 0) atomicAdd(&gsum[curg * 128 + o], acc);
}

// one wave per graph: logits = (gsum/cnt) @ Wl + bl; log_softmax over 16 classes
__global__ void k_head(const float* __restrict__ gsum, const int* __restrict__ gstart,
                       const float* __restrict__ Wl, const float* __restrict__ bl,
                       float* __restrict__ out) {
  int wave = threadIdx.x >> 6, lane = threadIdx.x & 63;
  int g = blockIdx.x * 4 + wave;
  if (g >= NG) return;
  int c = lane & 15, part = lane >> 4;
  float acc = 0.f;
#pragma unroll
  for (int kk = 0; kk < 32; ++kk) {
    int k = part * 32 + kk;
    acc += gsum[g * 128 + k] * Wl[k * NC + c];
  }
  acc += __shfl_xor(acc, 16);
  acc += __shfl_xor(acc, 32);
  int cnt = gstart[g + 1] - gstart[g];
  float inv = 1.0f / (float)max(cnt, 1);
  float logit = acc * inv + bl[c];
  float m = logit;
#pragma unroll
  for (int d = 1; d < 16; d <<= 1) m = fmaxf(m, __shfl_xor(m, d));
  float ex = expf(logit - m), s = ex;
#pragma unroll
  for (int d = 1; d < 16; d <<= 1) s += __shfl_xor(s, d);
  if (lane < 16) out[g * NC + lane] = logit - m - logf(s);
}

extern "C" void kernel_launch(void* const* d_in, const int* in_sizes, int n_in,
                              void* d_out, int out_size, void* d_ws, size_t ws_size,
                              hipStream_t stream) {
  const float* x = (const float*)d_in[0];
  const int* ei = (const int*)d_in[1];
  const int* batch = (const int*)d_in[2];
  const float* W1 = (const float*)d_in[3];
  const float* b1 = (const float*)d_in[4];
  const float* W2 = (const float*)d_in[5];
  const float* b2 = (const float*)d_in[6];
  const float* W3 = (const float*)d_in[7];
  const float* b3 = (const float*)d_in[8];
  const float* Wl = (const float*)d_in[9];
  const float* bl = (const float*)d_in[10];
  const int* src = ei;
  const int* dst = ei + NE;

  // workspace layout; zero range = [cnt, gsum] contiguous
  int* cnt = (int*)d_ws;                    // NN*HC
  float* gsum = (float*)(cnt + NN * HC);    // NG*128
  int* fillc = (int*)(gsum + NG * 128);     // NN*HC (fully init'd by k_scan3)
  int* count = fillc + NN * HC;             // NN
  int* offs = count + NN;                   // NN
  int* gstart = offs + NN;                  // NG+2
  int* bsum = gstart + NG + 2;              // 1024
  int* bpref = bsum + 1024;                 // 1024
  float* dinv = (float*)(bpref + 1024);     // NN
  int* csr = (int*)(dinv + NN);             // NE (src only)
  float* bufA = (float*)(csr + NE);         // NN*64
  float* bufH = bufA + (size_t)NN * 64;     // NN*64

  const int B = 256;
  const int NB_SCAN = cdiv(NN, 256);  // 391
  const int n_zero_elems = NN * HC + NG * 128;

  // CSR build + norms + graph bounds
  k_zero_i<<<cdiv(n_zero_elems, B), B, 0, stream>>>(cnt, n_zero_elems);
  k_hist8<<<cdiv(NE, B), B, 0, stream>>>(dst, cnt);
  k_bounds<<<cdiv(NN + 1, B), B, 0, stream>>>(batch, gstart);
  k_reduce<<<cdiv(NN, B), B, 0, stream>>>(cnt, count, dinv);
  k_scan1<<<NB_SCAN, 256, 0, stream>>>(count, offs, bsum, NN);
  k_scan2<<<1, 512, 0, stream>>>(bsum, bpref, NB_SCAN);
  k_scan3<<<cdiv(NN, B), B, 0, stream>>>(offs, bpref, cnt, fillc);
  k_fill<<<cdiv(NE, B), B, 0, stream>>>(src, dst, fillc, csr);

  // layer 1 (transform-first): t1 = x@W1; h1 = relu(agg(t1)+b1)
  k_dense<13, 16, false><<<cdiv((long long)NN * 16, B), B, 0, stream>>>(x, W1, b1, bufH, NN);
  k_agg<16, 16, true><<<cdiv(NN, 16), B, 0, stream>>>(bufH, csr, offs, count, dinv, b1, bufA);
  // layer 2: agg(h1) -> dense 16->64 (+bias+relu)
  k_agg<16, 16, false><<<cdiv(NN, 16), B, 0, stream>>>(bufA, csr, offs, count, dinv, nullptr, bufH);
  k_dense<16, 64, true><<<cdiv((long long)NN * 64, B), B, 0, stream>>>(bufH, W2, b2, bufA, NN);
  // layer 3: agg(h2) -> fused dense(64->128)+relu+pool
  k_agg<64, 64, false><<<cdiv(NN, 4), B, 0, stream>>>(bufA, csr, offs, count, dinv, nullptr, bufH);
  k_dense3_pool3<<<cdiv(NN, D3_NPB), 256, 0, stream>>>(bufH, W3, b3, batch, gsum);

  // head
  k_head<<<NG / 4, B, 0, stream>>>(gsum, gstart, Wl, bl, (float*)d_out);
}

// Round 8
// 379.848 us; speedup vs baseline: 1.2514x; 1.2514x over previous
//
#include <hip/hip_runtime.h>

#define NN 100000
#define NE 1600000
#define NG 512
#define NC 16
#define HC 8  // histogram copies

static inline int cdiv(long long a, int b) { return (int)((a + b - 1) / b); }

__device__ __forceinline__ float bf_lo(unsigned int u) { return __uint_as_float(u << 16); }
__device__ __forceinline__ float bf_hi(unsigned int u) { return __uint_as_float(u & 0xffff0000u); }
__device__ __forceinline__ unsigned int pack_bf16(float x, float y) {
  unsigned int xb = __float_as_uint(x), yb = __float_as_uint(y);
  xb = (xb + 0x7fffu + ((xb >> 16) & 1u)) >> 16;
  yb = (yb + 0x7fffu + ((yb >> 16) & 1u)) >> 16;
  return xb | (yb << 16);
}

__global__ void k_zero_i(int* p, int n) {
  int i = blockIdx.x * blockDim.x + threadIdx.x;
  if (i < n) p[i] = 0;
}

// 8-way replicated in-degree histogram: cnt[d*HC + (e&7)]
__global__ void k_hist8(const int* __restrict__ dst, int* __restrict__ cnt) {
  int e = blockIdx.x * blockDim.x + threadIdx.x;
  if (e < NE) atomicAdd(&cnt[dst[e] * HC + (e & (HC - 1))], 1);
}

// sum copies -> count; copies -> per-copy exclusive prefix (in place); dinv
__global__ void k_reduce(int* __restrict__ cnt, int* __restrict__ count,
                         float* __restrict__ dinv) {
  int i = blockIdx.x * blockDim.x + threadIdx.x;
  if (i >= NN) return;
  int s = 0;
#pragma unroll
  for (int c = 0; c < HC; ++c) {
    int v = cnt[i * HC + c];
    cnt[i * HC + c] = s;
    s += v;
  }
  count[i] = s;
  dinv[i] = rsqrtf((float)(s + 1));  // +1 self loop
}

// graph boundaries from sorted batch: gstart[g] = first node index with batch >= g
__global__ void k_bounds(const int* __restrict__ batch, int* __restrict__ gstart) {
  int i = blockIdx.x * blockDim.x + threadIdx.x;
  if (i > NN) return;
  int b = (i < NN) ? batch[i] : NG;
  int bp = (i > 0) ? batch[i - 1] : -1;
  for (int g = bp + 1; g <= b; ++g) gstart[g] = i;
}

// exclusive scan, 256/block; bsum gets block totals
__global__ void k_scan1(const int* __restrict__ in, int* __restrict__ out,
                        int* __restrict__ bsum, int n) {
  __shared__ int s[256];
  int t = threadIdx.x, i = blockIdx.x * 256 + t;
  int v = (i < n) ? in[i] : 0;
  s[t] = v;
  __syncthreads();
  for (int d = 1; d < 256; d <<= 1) {
    int a = (t >= d) ? s[t - d] : 0;
    __syncthreads();
    s[t] += a;
    __syncthreads();
  }
  if (i < n) out[i] = s[t] - v;  // exclusive
  if (t == 255) bsum[blockIdx.x] = s[255];
}

// single-block exclusive scan over <=512 values
__global__ void k_scan2(const int* __restrict__ in, int* __restrict__ out, int nb) {
  __shared__ int s[512];
  int t = threadIdx.x;
  int v = (t < nb) ? in[t] : 0;
  s[t] = v;
  __syncthreads();
  for (int d = 1; d < 512; d <<= 1) {
    int a = (t >= d) ? s[t - d] : 0;
    __syncthreads();
    s[t] += a;
    __syncthreads();
  }
  if (t < nb) out[t] = s[t] - v;
}

__global__ void k_scan3(int* __restrict__ out, const int* __restrict__ bpref, int n) {
  int i = blockIdx.x * blockDim.x + threadIdx.x;
  if (i < n) out[i] += bpref[i >> 8];
}

// scatter edges into CSR slots using per-copy prefixes (round-6 measured-best form)
__global__ void k_fill(const int* __restrict__ src, const int* __restrict__ dst,
                       const int* __restrict__ offs, const int* __restrict__ cnt,
                       int* __restrict__ fillc, const float* __restrict__ dinv,
                       int2* __restrict__ csr) {
  int e = blockIdx.x * blockDim.x + threadIdx.x;
  if (e >= NE) return;
  int s = src[e], d = dst[e];
  int c = e & (HC - 1);
  int pos = offs[d] + cnt[d * HC + c] + atomicAdd(&fillc[d * HC + c], 1);
  csr[pos] = make_int2(s, __float_as_int(dinv[s] * dinv[d]));
}

// gather-reduce aggregation (fp32 rows), int2 csr. BR: fused bias+relu.
template <int F, int LPN, bool BR>
__global__ void k_agg(const float* __restrict__ h, const int2* __restrict__ csr,
                      const int* __restrict__ offs, const int* __restrict__ count,
                      const float* __restrict__ dinv, const float* __restrict__ bias,
                      float* __restrict__ out) {
  int wave = threadIdx.x >> 6, lane = threadIdx.x & 63;
  const int NPW = 64 / LPN;  // nodes per wave
  int i = (blockIdx.x * 4 + wave) * NPW + ((LPN == 64) ? 0 : (lane >> 4));
  int f = lane & (LPN - 1);
  if (i >= NN) return;
  int off = offs[i], cnt = count[i];
  float acc0 = 0.f, acc1 = 0.f, acc2 = 0.f, acc3 = 0.f;
  int j = 0;
  for (; j + 3 < cnt; j += 4) {
    int2 p0 = csr[off + j];
    int2 p1 = csr[off + j + 1];
    int2 p2 = csr[off + j + 2];
    int2 p3 = csr[off + j + 3];
    acc0 += h[(size_t)p0.x * F + f] * __int_as_float(p0.y);
    acc1 += h[(size_t)p1.x * F + f] * __int_as_float(p1.y);
    acc2 += h[(size_t)p2.x * F + f] * __int_as_float(p2.y);
    acc3 += h[(size_t)p3.x * F + f] * __int_as_float(p3.y);
  }
  for (; j < cnt; ++j) {
    int2 p0 = csr[off + j];
    acc0 += h[(size_t)p0.x * F + f] * __int_as_float(p0.y);
  }
  float di = dinv[i];
  acc0 += h[(size_t)i * F + f] * di * di;  // self loop
  float v = (acc0 + acc1) + (acc2 + acc3);
  if (BR) v = fmaxf(v + bias[f], 0.f);
  out[(size_t)i * F + f] = v;
}

// bf16 gather-reduce for F=64: 32 lanes/node, 2 packed features/lane
__global__ void k_agg_b64(const unsigned int* __restrict__ h, const int2* __restrict__ csr,
                          const int* __restrict__ offs, const int* __restrict__ count,
                          const float* __restrict__ dinv, float* __restrict__ out) {
  int wave = threadIdx.x >> 6, lane = threadIdx.x & 63;
  int i = (blockIdx.x * 4 + wave) * 2 + (lane >> 5);
  int fp = lane & 31;  // feature pair
  if (i >= NN) return;
  int off = offs[i], cnt = count[i];
  float a0 = 0.f, a1 = 0.f, b0 = 0.f, b1 = 0.f;
  float c0 = 0.f, c1 = 0.f, d0 = 0.f, d1 = 0.f;
  int j = 0;
  for (; j + 3 < cnt; j += 4) {
    int2 p0 = csr[off + j], p1 = csr[off + j + 1];
    int2 p2 = csr[off + j + 2], p3 = csr[off + j + 3];
    unsigned int h0 = h[(size_t)p0.x * 32 + fp];
    unsigned int h1 = h[(size_t)p1.x * 32 + fp];
    unsigned int h2 = h[(size_t)p2.x * 32 + fp];
    unsigned int h3 = h[(size_t)p3.x * 32 + fp];
    float w0 = __int_as_float(p0.y), w1 = __int_as_float(p1.y);
    float w2 = __int_as_float(p2.y), w3 = __int_as_float(p3.y);
    a0 += bf_lo(h0) * w0; a1 += bf_hi(h0) * w0;
    b0 += bf_lo(h1) * w1; b1 += bf_hi(h1) * w1;
    c0 += bf_lo(h2) * w2; c1 += bf_hi(h2) * w2;
    d0 += bf_lo(h3) * w3; d1 += bf_hi(h3) * w3;
  }
  for (; j < cnt; ++j) {
    int2 p0 = csr[off + j];
    unsigned int h0 = h[(size_t)p0.x * 32 + fp];
    float w0 = __int_as_float(p0.y);
    a0 += bf_lo(h0) * w0; a1 += bf_hi(h0) * w0;
  }
  float di = dinv[i];
  unsigned int hs = h[(size_t)i * 32 + fp];
  a0 += bf_lo(hs) * di * di; a1 += bf_hi(hs) * di * di;
  float2 r = make_float2((a0 + b0) + (c0 + d0), (a1 + b1) + (c1 + d1));
  ((float2*)out)[(size_t)i * 32 + fp] = r;
}

// out[i,o] = a[i,:]@W[:,o] (+bias, relu if BR)
template <int FIN, int FOUT, bool BR>
__global__ void k_dense(const float* __restrict__ a, const float* __restrict__ W,
                        const float* __restrict__ b, float* __restrict__ out, int n) {
  __shared__ float sW[FIN * FOUT];
  __shared__ float sb[FOUT];
  for (int t = threadIdx.x; t < FIN * FOUT; t += blockDim.x) sW[t] = W[t];
  if (BR)
    for (int t = threadIdx.x; t < FOUT; t += blockDim.x) sb[t] = b[t];
  __syncthreads();
  int idx = blockIdx.x * blockDim.x + threadIdx.x;
  int i = idx / FOUT, o = idx % FOUT;
  if (i >= n) return;
  float acc = BR ? sb[o] : 0.f;
#pragma unroll
  for (int k = 0; k < FIN; ++k) acc += a[(size_t)i * FIN + k] * sW[k * FOUT + o];
  out[idx] = BR ? fmaxf(acc, 0.0f) : acc;
}

// dense 16->64 with bias+relu, bf16-packed output (2 outputs/thread)
__global__ void k_dense2_b(const float* __restrict__ a, const float* __restrict__ W,
                           const float* __restrict__ b, unsigned int* __restrict__ out,
                           int n) {
  __shared__ float sW[16 * 64];
  __shared__ float sb[64];
  for (int t = threadIdx.x; t < 16 * 64; t += blockDim.x) sW[t] = W[t];
  for (int t = threadIdx.x; t < 64; t += blockDim.x) sb[t] = b[t];
  __syncthreads();
  int idx = blockIdx.x * blockDim.x + threadIdx.x;
  int i = idx >> 5, op = idx & 31;
  if (i >= n) return;
  float acc0 = sb[2 * op], acc1 = sb[2 * op + 1];
#pragma unroll
  for (int k = 0; k < 16; ++k) {
    float av = a[(size_t)i * 16 + k];
    acc0 += av * sW[k * 64 + 2 * op];
    acc1 += av * sW[k * 64 + 2 * op + 1];
  }
  out[(size_t)i * 32 + op] = pack_bf16(fmaxf(acc0, 0.f), fmaxf(acc1, 0.f));
}

// fused dense3(64->128)+relu+segmented mean-pool over sorted batch.
#define D3_NPB 128  // nodes per block
#define D3_CH 32    // nodes per staged chunk
__global__ void k_dense3_pool3(const float* __restrict__ a, const float* __restrict__ W3,
                               const float* __restrict__ b3, const int* __restrict__ batch,
                               float* __restrict__ gsum) {
  __shared__ float sa[D3_CH * 64];
  int t = threadIdx.x;
  int half = t >> 7, o = t & 127;
  float wcol[64];
#pragma unroll
  for (int k = 0; k < 64; ++k) wcol[k] = W3[k * 128 + o];
  float bias = b3[o];
  int base = blockIdx.x * D3_NPB;
  float acc = 0.f;
  int curg = -1;
#pragma unroll 1
  for (int c0 = 0; c0 < D3_NPB; c0 += D3_CH) {
    __syncthreads();
#pragma unroll
    for (int r = 0; r < (D3_CH * 16) / 256; ++r) {
      int idx = r * 256 + t;  // float4 index within chunk
      int node = base + c0 + (idx >> 4);
      float4 v = make_float4(0.f, 0.f, 0.f, 0.f);
      if (node < NN) v = ((const float4*)(a + (size_t)node * 64))[idx & 15];
      ((float4*)sa)[idx] = v;
    }
    __syncthreads();
#pragma unroll 1
    for (int j = 0; j < D3_CH / 2; ++j) {
      int local = half * (D3_CH / 2) + j;
      int n = base + c0 + local;
      if (n >= NN) break;
      const float* row = sa + local * 64;
      float v = bias;
#pragma unroll
      for (int q = 0; q < 16; ++q) {
        float4 av = ((const float4*)row)[q];
        v += av.x * wcol[4 * q] + av.y * wcol[4 * q + 1] + av.z * wcol[4 * q + 2] +
             av.w * wcol[4 * q + 3];
      }
      int g = batch[n];
      if (g != curg) {
        if (curg >= 0) atomicAdd(&gsum[curg * 128 + o], acc);
        curg = g;
        acc = 0.f;
      }
      acc += fmaxf(v, 0.f);
    }
  }
  if (curg >= 0) atomicAdd(&gsum[curg * 128 + o], acc);
}

// one wave per graph: logits = (gsum/cnt) @ Wl + bl; log_softmax over 16 classes
__global__ void k_head(const float* __restrict__ gsum, const int* __restrict__ gstart,
                       const float* __restrict__ Wl, const float* __restrict__ bl,
                       float* __restrict__ out) {
  int wave = threadIdx.x >> 6, lane = threadIdx.x & 63;
  int g = blockIdx.x * 4 + wave;
  if (g >= NG) return;
  int c = lane & 15, part = lane >> 4;
  float acc = 0.f;
#pragma unroll
  for (int kk = 0; kk < 32; ++kk) {
    int k = part * 32 + kk;
    acc += gsum[g * 128 + k] * Wl[k * NC + c];
  }
  acc += __shfl_xor(acc, 16);
  acc += __shfl_xor(acc, 32);
  int cnt = gstart[g + 1] - gstart[g];
  float inv = 1.0f / (float)max(cnt, 1);
  float logit = acc * inv + bl[c];
  float m = logit;
#pragma unroll
  for (int d = 1; d < 16; d <<= 1) m = fmaxf(m, __shfl_xor(m, d));
  float ex = expf(logit - m), s = ex;
#pragma unroll
  for (int d = 1; d < 16; d <<= 1) s += __shfl_xor(s, d);
  if (lane < 16) out[g * NC + lane] = logit - m - logf(s);
}

extern "C" void kernel_launch(void* const* d_in, const int* in_sizes, int n_in,
                              void* d_out, int out_size, void* d_ws, size_t ws_size,
                              hipStream_t stream) {
  const float* x = (const float*)d_in[0];
  const int* ei = (const int*)d_in[1];
  const int* batch = (const int*)d_in[2];
  const float* W1 = (const float*)d_in[3];
  const float* b1 = (const float*)d_in[4];
  const float* W2 = (const float*)d_in[5];
  const float* b2 = (const float*)d_in[6];
  const float* W3 = (const float*)d_in[7];
  const float* b3 = (const float*)d_in[8];
  const float* Wl = (const float*)d_in[9];
  const float* bl = (const float*)d_in[10];
  const int* src = ei;
  const int* dst = ei + NE;

  // workspace layout; zero range = [cnt, fillc, gsum] contiguous
  int* cnt = (int*)d_ws;                    // NN*HC
  int* fillc = cnt + NN * HC;               // NN*HC
  float* gsum = (float*)(fillc + NN * HC);  // NG*128
  int* count = (int*)(gsum + NG * 128);     // NN
  int* offs = count + NN;                   // NN
  int* gstart = offs + NN;                  // NG+2
  int* bsum = gstart + NG + 2;              // 1024
  int* bpref = bsum + 1024;                 // 1024
  float* dinv = (float*)(bpref + 1024);     // NN
  int2* csr = (int2*)(dinv + NN);           // NE int2 (8B aligned: offset even)
  float* t1 = (float*)(csr + NE);           // NN*16 (also reused as t2)
  float* h1 = t1 + (size_t)NN * 16;         // NN*16
  unsigned int* h2b = (unsigned int*)(h1 + (size_t)NN * 16);  // NN*32 (bf16x2)
  float* t3 = (float*)(h2b + (size_t)NN * 32);                // NN*64

  const int B = 256;
  const int NB_SCAN = cdiv(NN, 256);  // 391
  const int n_zero_elems = 2 * NN * HC + NG * 128;

  // CSR build + norms + graph bounds
  k_zero_i<<<cdiv(n_zero_elems, B), B, 0, stream>>>(cnt, n_zero_elems);
  k_hist8<<<cdiv(NE, B), B, 0, stream>>>(dst, cnt);
  k_bounds<<<cdiv(NN + 1, B), B, 0, stream>>>(batch, gstart);
  k_reduce<<<cdiv(NN, B), B, 0, stream>>>(cnt, count, dinv);
  k_scan1<<<NB_SCAN, 256, 0, stream>>>(count, offs, bsum, NN);
  k_scan2<<<1, 512, 0, stream>>>(bsum, bpref, NB_SCAN);
  k_scan3<<<cdiv(NN, B), B, 0, stream>>>(offs, bpref, NN);
  k_fill<<<cdiv(NE, B), B, 0, stream>>>(src, dst, offs, cnt, fillc, dinv, csr);

  // layer 1 (transform-first): t1 = x@W1; h1 = relu(agg(t1)+b1)
  k_dense<13, 16, false><<<cdiv((long long)NN * 16, B), B, 0, stream>>>(x, W1, b1, t1, NN);
  k_agg<16, 16, true><<<cdiv(NN, 16), B, 0, stream>>>(t1, csr, offs, count, dinv, b1, h1);
  // layer 2: t2 = agg(h1) (reuse t1 buffer); h2 = bf16(relu(t2@W2+b2))
  k_agg<16, 16, false><<<cdiv(NN, 16), B, 0, stream>>>(h1, csr, offs, count, dinv, nullptr, t1);
  k_dense2_b<<<cdiv((long long)NN * 32, B), B, 0, stream>>>(t1, W2, b2, h2b, NN);
  // layer 3: t3 = agg_bf16(h2); fused dense(64->128)+relu+pool
  k_agg_b64<<<cdiv(NN, 8), B, 0, stream>>>(h2b, csr, offs, count, dinv, t3);
  k_dense3_pool3<<<cdiv(NN, D3_NPB), 256, 0, stream>>>(t3, W3, b3, batch, gsum);

  // head
  k_head<<<NG / 4, B, 0, stream>>>(gsum, gstart, Wl, bl, (float*)d_out);
}

// Round 9
// 319.460 us; speedup vs baseline: 1.4880x; 1.1890x over previous
//
#include <hip/hip_runtime.h>
#include <hip/hip_fp16.h>

#define NN 100000
#define NE 1600000
#define NG 512
#define NC 16
#define HC 8  // histogram copies

static inline int cdiv(long long a, int b) { return (int)((a + b - 1) / b); }

__device__ __forceinline__ unsigned int pack_f16(float x, float y) {
  __half2 h = __floats2half2_rn(x, y);
  return *reinterpret_cast<unsigned int*>(&h);
}
__device__ __forceinline__ float2 unpack_f16(unsigned int u) {
  __half2 h = *reinterpret_cast<__half2*>(&u);
  return __half22float2(h);
}

__global__ void k_zero_i(int* p, int n) {
  int i = blockIdx.x * blockDim.x + threadIdx.x;
  if (i < n) p[i] = 0;
}

// 8-way replicated in-degree histogram; rank[e] = arrival order within (d,c) bucket
__global__ void k_hist8(const int* __restrict__ dst, int* __restrict__ cnt,
                        int* __restrict__ rank) {
  int e = blockIdx.x * blockDim.x + threadIdx.x;
  if (e < NE) rank[e] = atomicAdd(&cnt[dst[e] * HC + (e & (HC - 1))], 1);
}

// sum copies -> count; copies -> per-copy exclusive prefix (in place); dinv
__global__ void k_reduce(int* __restrict__ cnt, int* __restrict__ count,
                         float* __restrict__ dinv) {
  int i = blockIdx.x * blockDim.x + threadIdx.x;
  if (i >= NN) return;
  int s = 0;
#pragma unroll
  for (int c = 0; c < HC; ++c) {
    int v = cnt[i * HC + c];
    cnt[i * HC + c] = s;
    s += v;
  }
  count[i] = s;
  dinv[i] = rsqrtf((float)(s + 1));  // +1 self loop
}

// graph boundaries from sorted batch: gstart[g] = first node index with batch >= g
__global__ void k_bounds(const int* __restrict__ batch, int* __restrict__ gstart) {
  int i = blockIdx.x * blockDim.x + threadIdx.x;
  if (i > NN) return;
  int b = (i < NN) ? batch[i] : NG;
  int bp = (i > 0) ? batch[i - 1] : -1;
  for (int g = bp + 1; g <= b; ++g) gstart[g] = i;
}

// exclusive scan, 256/block; bsum gets block totals
__global__ void k_scan1(const int* __restrict__ in, int* __restrict__ out,
                        int* __restrict__ bsum, int n) {
  __shared__ int s[256];
  int t = threadIdx.x, i = blockIdx.x * 256 + t;
  int v = (i < n) ? in[i] : 0;
  s[t] = v;
  __syncthreads();
  for (int d = 1; d < 256; d <<= 1) {
    int a = (t >= d) ? s[t - d] : 0;
    __syncthreads();
    s[t] += a;
    __syncthreads();
  }
  if (i < n) out[i] = s[t] - v;  // exclusive
  if (t == 255) bsum[blockIdx.x] = s[255];
}

// single-block exclusive scan over <=512 values
__global__ void k_scan2(const int* __restrict__ in, int* __restrict__ out, int nb) {
  __shared__ int s[512];
  int t = threadIdx.x;
  int v = (t < nb) ? in[t] : 0;
  s[t] = v;
  __syncthreads();
  for (int d = 1; d < 512; d <<= 1) {
    int a = (t >= d) ? s[t - d] : 0;
    __syncthreads();
    s[t] += a;
    __syncthreads();
  }
  if (t < nb) out[t] = s[t] - v;
}

__global__ void k_scan3(int* __restrict__ out, const int* __restrict__ bpref, int n) {
  int i = blockIdx.x * blockDim.x + threadIdx.x;
  if (i < n) out[i] += bpref[i >> 8];
}

// scatter edges into CSR slots; NO atomics (rank precomputed in k_hist8)
__global__ void k_fill(const int* __restrict__ src, const int* __restrict__ dst,
                       const int* __restrict__ offs, const int* __restrict__ cnt,
                       const int* __restrict__ rank, const float* __restrict__ dinv,
                       int2* __restrict__ csr) {
  int e = blockIdx.x * blockDim.x + threadIdx.x;
  if (e >= NE) return;
  int s = src[e], d = dst[e];
  int pos = offs[d] + cnt[d * HC + (e & (HC - 1))] + rank[e];
  csr[pos] = make_int2(s, __float_as_int(dinv[s] * dinv[d]));
}

// gather-reduce aggregation (fp32 rows), int2 csr. BR: fused bias+relu.
template <int F, int LPN, bool BR>
__global__ void k_agg(const float* __restrict__ h, const int2* __restrict__ csr,
                      const int* __restrict__ offs, const int* __restrict__ count,
                      const float* __restrict__ dinv, const float* __restrict__ bias,
                      float* __restrict__ out) {
  int wave = threadIdx.x >> 6, lane = threadIdx.x & 63;
  const int NPW = 64 / LPN;  // nodes per wave
  int i = (blockIdx.x * 4 + wave) * NPW + ((LPN == 64) ? 0 : (lane >> 4));
  int f = lane & (LPN - 1);
  if (i >= NN) return;
  int off = offs[i], cnt = count[i];
  float acc0 = 0.f, acc1 = 0.f, acc2 = 0.f, acc3 = 0.f;
  int j = 0;
  for (; j + 3 < cnt; j += 4) {
    int2 p0 = csr[off + j];
    int2 p1 = csr[off + j + 1];
    int2 p2 = csr[off + j + 2];
    int2 p3 = csr[off + j + 3];
    acc0 += h[(size_t)p0.x * F + f] * __int_as_float(p0.y);
    acc1 += h[(size_t)p1.x * F + f] * __int_as_float(p1.y);
    acc2 += h[(size_t)p2.x * F + f] * __int_as_float(p2.y);
    acc3 += h[(size_t)p3.x * F + f] * __int_as_float(p3.y);
  }
  for (; j < cnt; ++j) {
    int2 p0 = csr[off + j];
    acc0 += h[(size_t)p0.x * F + f] * __int_as_float(p0.y);
  }
  float di = dinv[i];
  acc0 += h[(size_t)i * F + f] * di * di;  // self loop
  float v = (acc0 + acc1) + (acc2 + acc3);
  if (BR) v = fmaxf(v + bias[f], 0.f);
  out[(size_t)i * F + f] = v;
}

// fp16 gather-reduce for F=64: 32 lanes/node, 2 packed features/lane
__global__ void k_agg_b64(const unsigned int* __restrict__ h, const int2* __restrict__ csr,
                          const int* __restrict__ offs, const int* __restrict__ count,
                          const float* __restrict__ dinv, float* __restrict__ out) {
  int wave = threadIdx.x >> 6, lane = threadIdx.x & 63;
  int i = (blockIdx.x * 4 + wave) * 2 + (lane >> 5);
  int fp = lane & 31;  // feature pair
  if (i >= NN) return;
  int off = offs[i], cnt = count[i];
  float a0 = 0.f, a1 = 0.f, b0 = 0.f, b1 = 0.f;
  float c0 = 0.f, c1 = 0.f, d0 = 0.f, d1 = 0.f;
  int j = 0;
  for (; j + 3 < cnt; j += 4) {
    int2 p0 = csr[off + j], p1 = csr[off + j + 1];
    int2 p2 = csr[off + j + 2], p3 = csr[off + j + 3];
    float2 f0 = unpack_f16(h[(size_t)p0.x * 32 + fp]);
    float2 f1 = unpack_f16(h[(size_t)p1.x * 32 + fp]);
    float2 f2 = unpack_f16(h[(size_t)p2.x * 32 + fp]);
    float2 f3 = unpack_f16(h[(size_t)p3.x * 32 + fp]);
    float w0 = __int_as_float(p0.y), w1 = __int_as_float(p1.y);
    float w2 = __int_as_float(p2.y), w3 = __int_as_float(p3.y);
    a0 += f0.x * w0; a1 += f0.y * w0;
    b0 += f1.x * w1; b1 += f1.y * w1;
    c0 += f2.x * w2; c1 += f2.y * w2;
    d0 += f3.x * w3; d1 += f3.y * w3;
  }
  for (; j < cnt; ++j) {
    int2 p0 = csr[off + j];
    float2 f0 = unpack_f16(h[(size_t)p0.x * 32 + fp]);
    float w0 = __int_as_float(p0.y);
    a0 += f0.x * w0; a1 += f0.y * w0;
  }
  float di = dinv[i];
  float2 fs = unpack_f16(h[(size_t)i * 32 + fp]);
  a0 += fs.x * di * di; a1 += fs.y * di * di;
  float2 r = make_float2((a0 + b0) + (c0 + d0), (a1 + b1) + (c1 + d1));
  ((float2*)out)[(size_t)i * 32 + fp] = r;
}

// out[i,o] = a[i,:]@W[:,o] (+bias, relu if BR)
template <int FIN, int FOUT, bool BR>
__global__ void k_dense(const float* __restrict__ a, const float* __restrict__ W,
                        const float* __restrict__ b, float* __restrict__ out, int n) {
  __shared__ float sW[FIN * FOUT];
  __shared__ float sb[FOUT];
  for (int t = threadIdx.x; t < FIN * FOUT; t += blockDim.x) sW[t] = W[t];
  if (BR)
    for (int t = threadIdx.x; t < FOUT; t += blockDim.x) sb[t] = b[t];
  __syncthreads();
  int idx = blockIdx.x * blockDim.x + threadIdx.x;
  int i = idx / FOUT, o = idx % FOUT;
  if (i >= n) return;
  float acc = BR ? sb[o] : 0.f;
#pragma unroll
  for (int k = 0; k < FIN; ++k) acc += a[(size_t)i * FIN + k] * sW[k * FOUT + o];
  out[idx] = BR ? fmaxf(acc, 0.0f) : acc;
}

// dense 16->64 with bias+relu, fp16-packed output (2 outputs/thread)
__global__ void k_dense2_b(const float* __restrict__ a, const float* __restrict__ W,
                           const float* __restrict__ b, unsigned int* __restrict__ out,
                           int n) {
  __shared__ float sW[16 * 64];
  __shared__ float sb[64];
  for (int t = threadIdx.x; t < 16 * 64; t += blockDim.x) sW[t] = W[t];
  for (int t = threadIdx.x; t < 64; t += blockDim.x) sb[t] = b[t];
  __syncthreads();
  int idx = blockIdx.x * blockDim.x + threadIdx.x;
  int i = idx >> 5, op = idx & 31;
  if (i >= n) return;
  float acc0 = sb[2 * op], acc1 = sb[2 * op + 1];
#pragma unroll
  for (int k = 0; k < 16; ++k) {
    float av = a[(size_t)i * 16 + k];
    acc0 += av * sW[k * 64 + 2 * op];
    acc1 += av * sW[k * 64 + 2 * op + 1];
  }
  out[(size_t)i * 32 + op] = pack_f16(fmaxf(acc0, 0.f), fmaxf(acc1, 0.f));
}

// fused dense3(64->128)+relu+segmented mean-pool; NO LDS.
// 2 waves per 16-node run; wave-uniform row reads (scalar-load friendly);
// W3 column held in 64 VGPRs per lane.
#define P4_NPW 16  // nodes per wave-pair run
__global__ __launch_bounds__(256) void k_dense3_pool4(
    const float* __restrict__ t3, const float* __restrict__ W3,
    const float* __restrict__ b3, const int* __restrict__ batch,
    float* __restrict__ gsum) {
  int wu = blockIdx.x * 4 + (threadIdx.x >> 6);  // global wave unit
  int lane = threadIdx.x & 63;
  int run = wu >> 1;
  int o = (wu & 1) * 64 + lane;  // output feature
  int n0 = run * P4_NPW;
  if (n0 >= NN) return;
  float wcol[64];
#pragma unroll
  for (int k = 0; k < 64; ++k) wcol[k] = W3[k * 128 + o];
  float bias = b3[o];
  float acc = 0.f;
  int curg = -1;
#pragma unroll 1
  for (int j = 0; j < P4_NPW; ++j) {
    int n = n0 + j;
    if (n >= NN) break;
    int nu = __builtin_amdgcn_readfirstlane(n);
    const float4* row = (const float4*)(t3 + (size_t)nu * 64);
    float v = bias;
#pragma unroll
    for (int q = 0; q < 16; ++q) {
      float4 r = row[q];  // wave-uniform address
      v += r.x * wcol[4 * q] + r.y * wcol[4 * q + 1] + r.z * wcol[4 * q + 2] +
           r.w * wcol[4 * q + 3];
    }
    int g = batch[nu];
    if (g != curg) {
      if (curg >= 0) atomicAdd(&gsum[curg * 128 + o], acc);
      curg = g;
      acc = 0.f;
    }
    acc += fmaxf(v, 0.f);
  }
  if (curg >= 0) atomicAdd(&gsum[curg * 128 + o], acc);
}

// one wave per graph: logits = (gsum/cnt) @ Wl + bl; log_softmax over 16 classes
__global__ void k_head(const float* __restrict__ gsum, const int* __restrict__ gstart,
                       const float* __restrict__ Wl, const float* __restrict__ bl,
                       float* __restrict__ out) {
  int wave = threadIdx.x >> 6, lane = threadIdx.x & 63;
  int g = blockIdx.x * 4 + wave;
  if (g >= NG) return;
  int c = lane & 15, part = lane >> 4;
  float acc = 0.f;
#pragma unroll
  for (int kk = 0; kk < 32; ++kk) {
    int k = part * 32 + kk;
    acc += gsum[g * 128 + k] * Wl[k * NC + c];
  }
  acc += __shfl_xor(acc, 16);
  acc += __shfl_xor(acc, 32);
  int cnt = gstart[g + 1] - gstart[g];
  float inv = 1.0f / (float)max(cnt, 1);
  float logit = acc * inv + bl[c];
  float m = logit;
#pragma unroll
  for (int d = 1; d < 16; d <<= 1) m = fmaxf(m, __shfl_xor(m, d));
  float ex = expf(logit - m), s = ex;
#pragma unroll
  for (int d = 1; d < 16; d <<= 1) s += __shfl_xor(s, d);
  if (lane < 16) out[g * NC + lane] = logit - m - logf(s);
}

extern "C" void kernel_launch(void* const* d_in, const int* in_sizes, int n_in,
                              void* d_out, int out_size, void* d_ws, size_t ws_size,
                              hipStream_t stream) {
  const float* x = (const float*)d_in[0];
  const int* ei = (const int*)d_in[1];
  const int* batch = (const int*)d_in[2];
  const float* W1 = (const float*)d_in[3];
  const float* b1 = (const float*)d_in[4];
  const float* W2 = (const float*)d_in[5];
  const float* b2 = (const float*)d_in[6];
  const float* W3 = (const float*)d_in[7];
  const float* b3 = (const float*)d_in[8];
  const float* Wl = (const float*)d_in[9];
  const float* bl = (const float*)d_in[10];
  const int* src = ei;
  const int* dst = ei + NE;

  // workspace layout; zero range = [cnt, gsum] contiguous
  int* cnt = (int*)d_ws;                    // NN*HC
  float* gsum = (float*)(cnt + NN * HC);    // NG*128
  int* count = (int*)(gsum + NG * 128);     // NN
  int* offs = count + NN;                   // NN
  int* gstart = offs + NN;                  // NG+2
  int* bsum = gstart + NG + 2;              // 1024
  int* bpref = bsum + 1024;                 // 1024
  float* dinv = (float*)(bpref + 1024);     // NN
  int2* csr = (int2*)(dinv + NN);           // NE int2 (8B aligned)
  float* t1 = (float*)(csr + NE);           // NN*16 (aliases rank until k_fill done)
  float* h1 = t1 + (size_t)NN * 16;         // NN*16
  unsigned int* h2b = (unsigned int*)(h1 + (size_t)NN * 16);  // NN*32 (fp16x2)
  float* t3 = (float*)(h2b + (size_t)NN * 32);                // NN*64
  int* rank = (int*)t1;  // NE ints; lifetime ends at k_fill, before t1 is written

  const int B = 256;
  const int NB_SCAN = cdiv(NN, 256);  // 391
  const int n_zero_elems = NN * HC + NG * 128;

  // CSR build + norms + graph bounds
  k_zero_i<<<cdiv(n_zero_elems, B), B, 0, stream>>>(cnt, n_zero_elems);
  k_hist8<<<cdiv(NE, B), B, 0, stream>>>(dst, cnt, rank);
  k_bounds<<<cdiv(NN + 1, B), B, 0, stream>>>(batch, gstart);
  k_reduce<<<cdiv(NN, B), B, 0, stream>>>(cnt, count, dinv);
  k_scan1<<<NB_SCAN, 256, 0, stream>>>(count, offs, bsum, NN);
  k_scan2<<<1, 512, 0, stream>>>(bsum, bpref, NB_SCAN);
  k_scan3<<<cdiv(NN, B), B, 0, stream>>>(offs, bpref, NN);
  k_fill<<<cdiv(NE, B), B, 0, stream>>>(src, dst, offs, cnt, rank, dinv, csr);

  // layer 1 (transform-first): t1 = x@W1; h1 = relu(agg(t1)+b1)
  k_dense<13, 16, false><<<cdiv((long long)NN * 16, B), B, 0, stream>>>(x, W1, b1, t1, NN);
  k_agg<16, 16, true><<<cdiv(NN, 16), B, 0, stream>>>(t1, csr, offs, count, dinv, b1, h1);
  // layer 2: t2 = agg(h1) (reuse t1 buffer); h2 = fp16(relu(t2@W2+b2))
  k_agg<16, 16, false><<<cdiv(NN, 16), B, 0, stream>>>(h1, csr, offs, count, dinv, nullptr, t1);
  k_dense2_b<<<cdiv((long long)NN * 32, B), B, 0, stream>>>(t1, W2, b2, h2b, NN);
  // layer 3: t3 = agg_fp16(h2); fused dense(64->128)+relu+pool (no LDS)
  k_agg_b64<<<cdiv(NN, 8), B, 0, stream>>>(h2b, csr, offs, count, dinv, t3);
  {
    int runs = cdiv(NN, P4_NPW);
    k_dense3_pool4<<<cdiv(runs * 2, 4), 256, 0, stream>>>(t3, W3, b3, batch, gsum);
  }

  // head
  k_head<<<NG / 4, B, 0, stream>>>(gsum, gstart, Wl, bl, (float*)d_out);
}